// Round 14
// baseline (345.612 us; speedup 1.0000x reference)
//
#include <hip/hip_runtime.h>
#include <hip/hip_bf16.h>
#include <cstddef>

// ---------------------------------------------------------------------------
// 3-layer MPNN, N=50000, E=800000, D=128, OUT=32.
// R14: bin/place reverted to R12 (atomic-free R13 regressed; bin's cost is
// structural, not atomics). NEW: aggregate fused INTO the layer GEMM --
// block aggregates its 64 rows (8-slot gather, fp32 regs) -> LDS chunk
// layout -> barrier -> R12 LDS-free MFMA GEMM with G a-frags from LDS.
// Deletes 3 launches + 25.6MB g round-trip per call.
//   h' = tanh([g|h]@[Wm;Wu]^T+bu); out = h3@Wout^T+b.
// CSR entry: (src:u16 | w:bf16<<16).
// ---------------------------------------------------------------------------

typedef __attribute__((ext_vector_type(8))) short short8;
typedef __attribute__((ext_vector_type(4))) float f32x4;
typedef unsigned short ushort_t;
typedef unsigned int uint_t;

#define BSH 8               // bucket shift: 256 nodes per bucket
#define BSZ 256             // nodes per bucket
#define CAPB 6144           // staged entries per bucket (mean 4096, >30 sigma)
#define TSTRIDE 16          // tails counter stride in ints (64B line each)
#define EPB 2048            // edges per bin block

__device__ inline ushort_t f2bf(float f) {  // round-to-nearest-even
    uint_t u = __float_as_uint(f);
    uint_t r = u + 0x7FFFu + ((u >> 16) & 1u);
    return (ushort_t)(r >> 16);
}
__device__ inline float bf_lo(uint_t u) { return __uint_as_float(u << 16); }
__device__ inline float bf_hi(uint_t u) { return __uint_as_float(u & 0xFFFF0000u); }
__device__ inline uint_t packbf(float a, float b) {
    return (uint_t)f2bf(a) | ((uint_t)f2bf(b) << 16);
}

// flag=1 -> int32 [2][E]; flag=0 -> int64 [2][E] (vectorized low-word read)
__device__ inline int get_dst(const int* __restrict__ ei, int e, int E, int f) {
    if (f) return ei[E + e];
    return ((const int2*)ei)[(size_t)E + e].x;
}
__device__ inline int get_src(const int* __restrict__ ei, int e, int E, int f) {
    if (f) return ei[e];
    return ((const int2*)ei)[e].x;
}

// ---------------------------------------------------------------------------
// Fused setup: zero tails+cursor | detect idx layout | swizzled bf16 weights
// | x -> bf16.
// ---------------------------------------------------------------------------
struct SetupArgs {
    const float* Wm0; const float* Wu0;
    const float* Wm1; const float* Wu1;
    const float* Wm2; const float* Wu2;
    const float* Wout;
    const float* x; const int* ei;
    ushort_t* wswz;    // 3 * 32768
    ushort_t* woswz;   // 4096
    ushort_t* xb;      // N*128
    int* tails;        // NB*TSTRIDE + cursor (zeroed together)
    int* flag;
    int N, E, TI;
    int ZT, WB, XB;
};
__global__ __launch_bounds__(256) void setup_kernel(SetupArgs a) {
    int bx = blockIdx.x, t = threadIdx.x;
    if (bx < a.ZT) {
        int i = bx * 256 + t;
        if (i < a.TI) a.tails[i] = 0;
        return;
    }
    bx -= a.ZT;
    if (bx == 0) {
        __shared__ int any;
        if (t == 0) any = 0;
        __syncthreads();
        int n = a.E < 2048 ? a.E : 2048;
        for (int i = t; i < n; i += 256)
            if (a.ei[2 * i + 1] != 0) any = 1;
        __syncthreads();
        if (t == 0) a.flag[0] = any;
        return;
    }
    bx -= 1;
    if (bx < a.WB) {
        int i = bx * 256 + t;
        if (i < 3 * 32768) {
            int l = i >> 15, r2 = i & 32767;
            int ct = r2 >> 12, ks = (r2 >> 9) & 7, lane = (r2 >> 3) & 63, j = r2 & 7;
            int col = ct * 16 + (lane & 15);
            int k = ks * 32 + (lane >> 4) * 8 + j;
            const float* Wm = l == 0 ? a.Wm0 : (l == 1 ? a.Wm1 : a.Wm2);
            const float* Wu = l == 0 ? a.Wu0 : (l == 1 ? a.Wu1 : a.Wu2);
            float v = k < 128 ? Wm[col * 128 + k] : Wu[col * 128 + (k - 128)];
            a.wswz[(size_t)l * 32768 + r2] = f2bf(v);
        } else if (i < 3 * 32768 + 4096) {
            int r2 = i - 3 * 32768;
            int ct = r2 >> 11, ks = (r2 >> 9) & 3, lane = (r2 >> 3) & 63, j = r2 & 7;
            int col = ct * 16 + (lane & 15);
            int k = ks * 32 + (lane >> 4) * 8 + j;
            a.woswz[r2] = f2bf(a.Wout[col * 128 + k]);
        }
        return;
    }
    bx -= a.WB;
    {
        int j = bx * 256 + t;
        if (j < a.N * 32) {
            float4 v = *(const float4*)(a.x + (size_t)j * 4);
            uint2 o;
            o.x = packbf(v.x, v.y);
            o.y = packbf(v.z, v.w);
            *(uint2*)(a.xb + (size_t)j * 4) = o;
        }
    }
}

// ---------------------------------------------------------------------------
// Phase A (R12): LDS multi-split binning, one global reserve atomic per
// (block,bucket). bucket = dst>>8.
// ---------------------------------------------------------------------------
__global__ __launch_bounds__(256) void bin_kernel(
    const int* __restrict__ ei, const float* __restrict__ ew,
    const int* __restrict__ flag, int* __restrict__ tails,
    uint2* __restrict__ staged, int E, int NB) {
    __shared__ uint2 ent[EPB];           // 16 KB
    __shared__ int cnt[256], cur[256], runbase[256];
    const int tid = threadIdx.x;
    const int e0 = blockIdx.x * EPB;
    const int nE = (E - e0) < EPB ? (E - e0) : EPB;
    const int f = flag[0];
    cnt[tid] = 0;
    cur[tid] = 0;
    __syncthreads();
    for (int i = tid; i < nE; i += 256) {
        int e = e0 + i;
        int s = get_src(ei, e, E, f);
        int d = get_dst(ei, e, E, f);
        uint2 v;
        v.x = (uint_t)s | ((uint_t)f2bf(ew[e]) << 16);
        v.y = (uint_t)d;
        ent[i] = v;
        atomicAdd(&cnt[d >> BSH], 1);    // LDS atomic
    }
    __syncthreads();
    if (tid < NB) {
        int c = cnt[tid];
        runbase[tid] = c ? atomicAdd(&tails[tid * TSTRIDE], c) : 0;
    }
    __syncthreads();
    for (int i = tid; i < nE; i += 256) {
        uint2 v = ent[i];
        int d = (int)v.y;
        int b = d >> BSH;
        int lp = atomicAdd(&cur[b], 1);  // LDS atomic
        int gp = runbase[b] + lp;
        if (gp < CAPB) {
            uint2 o;
            o.x = v.x;
            o.y = (uint_t)(d & (BSZ - 1));
            staged[(size_t)b * CAPB + gp] = o;
        }
    }
}

// ---------------------------------------------------------------------------
// Phase B (R12): one block per bucket, self-allocated CSR region via global
// cursor. LDS hist -> scan -> image -> coalesced flush. rowdeg = {beg,end}.
// ---------------------------------------------------------------------------
__global__ __launch_bounds__(256) void place_kernel(
    const uint2* __restrict__ staged, const int* __restrict__ tails,
    int* __restrict__ cursor, uint_t* __restrict__ csr,
    int2* __restrict__ rowdeg, int N) {
    __shared__ int cnt[256], cur[256], excl[256], sm[256];
    __shared__ int baseSh;
    __shared__ uint_t outb[CAPB];        // 24 KB
    const int b = blockIdx.x, tid = threadIdx.x;
    const int node0 = b << BSH;
    int tot = tails[b * TSTRIDE];
    tot = tot < CAPB ? tot : CAPB;
    cnt[tid] = 0;
    __syncthreads();
    const uint2* sp = staged + ((size_t)b * CAPB);
    for (int i = tid; i < tot; i += 256) atomicAdd(&cnt[sp[i].y], 1);
    __syncthreads();
    int c0 = cnt[tid];
    sm[tid] = c0;
    __syncthreads();
    for (int o = 1; o < 256; o <<= 1) {
        int v = tid >= o ? sm[tid - o] : 0;
        __syncthreads();
        sm[tid] += v;
        __syncthreads();
    }
    if (tid == 255) baseSh = atomicAdd(cursor, sm[255]);
    excl[tid] = sm[tid] - c0;
    cur[tid] = 0;
    __syncthreads();
    const int base = baseSh;
    for (int i = tid; i < tot; i += 256) {
        uint2 e = sp[i];
        int pos = excl[e.y] + atomicAdd(&cur[e.y], 1);
        outb[pos] = e.x;
    }
    __syncthreads();
    for (int i = tid; i < tot; i += 256) csr[base + i] = outb[i];
    if (node0 + tid < N) {
        int2 be;
        be.x = base + excl[tid];
        be.y = base + excl[tid] + c0;
        rowdeg[node0 + tid] = be;
    }
}

// ---------------------------------------------------------------------------
// Fused layer: per block of 64 rows,
//   phase 1: wave w aggregates its 16 nodes (8 edge-slots x 8 feat-lanes,
//            fp32 regs, shfl-reduce) -> LDS chunk layout (bf16).
//   phase 2: Hout = tanh([G|H] @ Wswz + bu) -- G a-frags from LDS
//            (lane-contiguous 16B ds_read, conflict-free), H from global.
// LDS chunk layout: flat[((rt*4+ks)*64 + kg*16 + m)*8 + j] for local row
// rt*16+m, k = ks*32+kg*8+j.
// ---------------------------------------------------------------------------
__global__ __launch_bounds__(256) void layer_fused(
    const uint_t* __restrict__ csr, const int2* __restrict__ rowdeg,
    const ushort_t* __restrict__ h, const ushort_t* __restrict__ Wswz,
    const float* __restrict__ bias, ushort_t* __restrict__ Hout, int N) {
    __shared__ ushort_t gs[64 * 128];    // 16 KB
    const int tid = threadIdx.x;
    const int lane = tid & 63;
    const int wv = tid >> 6;
    const int row0 = blockIdx.x * 64;

    // ---- phase 1: aggregate 16 nodes for this wave ----
    const int slot = lane >> 3, f8 = lane & 7;
    for (int t = 0; t < 16; ++t) {
        const int node = row0 + wv * 16 + t;
        float s[16];
#pragma unroll
        for (int k = 0; k < 16; ++k) s[k] = 0.f;
        if (node < N) {
            int2 be = rowdeg[node];
            for (int j = be.x + slot; j < be.y; j += 8) {
                uint_t p = csr[j];
                float w = bf_hi(p);
                const ushort_t* row = h + (size_t)(p & 0xFFFFu) * 128 + f8 * 16;
                uint4 v0 = *(const uint4*)(row);
                uint4 v1 = *(const uint4*)(row + 8);
                s[0] += w * bf_lo(v0.x);  s[1] += w * bf_hi(v0.x);
                s[2] += w * bf_lo(v0.y);  s[3] += w * bf_hi(v0.y);
                s[4] += w * bf_lo(v0.z);  s[5] += w * bf_hi(v0.z);
                s[6] += w * bf_lo(v0.w);  s[7] += w * bf_hi(v0.w);
                s[8] += w * bf_lo(v1.x);  s[9] += w * bf_hi(v1.x);
                s[10] += w * bf_lo(v1.y); s[11] += w * bf_hi(v1.y);
                s[12] += w * bf_lo(v1.z); s[13] += w * bf_hi(v1.z);
                s[14] += w * bf_lo(v1.w); s[15] += w * bf_hi(v1.w);
            }
        }
#pragma unroll
        for (int k = 0; k < 16; ++k) s[k] += __shfl_xor(s[k], 8, 64);
#pragma unroll
        for (int k = 0; k < 16; ++k) s[k] += __shfl_xor(s[k], 16, 64);
#pragma unroll
        for (int k = 0; k < 16; ++k) s[k] += __shfl_xor(s[k], 32, 64);
        if (slot == 0) {
            // lane f8 owns feats f8*16..+15 = chunks u=2*f8, 2*f8+1
#pragma unroll
            for (int c = 0; c < 2; ++c) {
                int u = 2 * f8 + c;             // 0..15: ks=u>>2, kg=u&3
                uint4 o;
                o.x = packbf(s[c * 8 + 0], s[c * 8 + 1]);
                o.y = packbf(s[c * 8 + 2], s[c * 8 + 3]);
                o.z = packbf(s[c * 8 + 4], s[c * 8 + 5]);
                o.w = packbf(s[c * 8 + 6], s[c * 8 + 7]);
                int addr = ((wv * 4 + (u >> 2)) * 64 + (u & 3) * 16 + t) * 8;
                *(uint4*)&gs[addr] = o;
            }
        }
    }
    __syncthreads();

    // ---- phase 2: GEMM ----
    const int m16 = lane & 15, kg = lane >> 4;
    const ushort_t* ah = h + (size_t)(row0 + wv * 16 + m16) * 128 + kg * 8;
    f32x4 acc[8];
#pragma unroll
    for (int ct = 0; ct < 8; ++ct) acc[ct] = (f32x4){0.f, 0.f, 0.f, 0.f};
#pragma unroll
    for (int ksp = 0; ksp < 8; ++ksp) {
        short8 a;
        if (ksp < 4)
            a = *(const short8*)&gs[((wv * 4 + ksp) * 64 + lane) * 8];
        else
            a = *(const short8*)(ah + (ksp & 3) * 32);
#pragma unroll
        for (int ct = 0; ct < 8; ++ct) {
            short8 b = *(const short8*)(Wswz + ((ct * 8 + ksp) * 64 + lane) * 8);
            acc[ct] = __builtin_amdgcn_mfma_f32_16x16x32_bf16(a, b, acc[ct], 0, 0, 0);
        }
    }
    const int rq = lane >> 4;
#pragma unroll
    for (int ct = 0; ct < 8; ++ct) {
        int col = ct * 16 + m16;
        float bv = bias[col];
#pragma unroll
        for (int reg = 0; reg < 4; ++reg) {
            int gr = row0 + wv * 16 + rq * 4 + reg;
            if (gr < N) Hout[(size_t)gr * 128 + col] = f2bf(tanhf(acc[ct][reg] + bv));
        }
    }
}

// LDS-free output GEMM: out[N,32] = H[N,128] @ Woswz + bout (fp32).
__global__ __launch_bounds__(256) void mfma_gemm_out(
    const ushort_t* __restrict__ H, const ushort_t* __restrict__ Wswz,
    const float* __restrict__ bias, float* __restrict__ C, int N) {
    const int tid = threadIdx.x;
    const int lane = tid & 63;
    const int row0 = blockIdx.x * 64 + (tid >> 6) * 16;
    const int m = lane & 15;
    const ushort_t* ah = H + (size_t)(row0 + m) * 128 + (lane >> 4) * 8;

    f32x4 acc[2];
#pragma unroll
    for (int ct = 0; ct < 2; ++ct) acc[ct] = (f32x4){0.f, 0.f, 0.f, 0.f};
#pragma unroll
    for (int ks = 0; ks < 4; ++ks) {
        short8 a = *(const short8*)(ah + ks * 32);
#pragma unroll
        for (int ct = 0; ct < 2; ++ct) {
            short8 b = *(const short8*)(Wswz + ((ct * 4 + ks) * 64 + lane) * 8);
            acc[ct] = __builtin_amdgcn_mfma_f32_16x16x32_bf16(a, b, acc[ct], 0, 0, 0);
        }
    }
    const int colL = lane & 15, rq = lane >> 4;
#pragma unroll
    for (int ct = 0; ct < 2; ++ct) {
        int col = ct * 16 + colL;
        float bv = bias[col];
#pragma unroll
        for (int reg = 0; reg < 4; ++reg) {
            int gr = row0 + rq * 4 + reg;
            if (gr < N) C[(size_t)gr * 32 + col] = acc[ct][reg] + bv;
        }
    }
}

extern "C" void kernel_launch(void* const* d_in, const int* in_sizes, int n_in,
                              void* d_out, int out_size, void* d_ws, size_t ws_size,
                              hipStream_t stream) {
    const float* x   = (const float*)d_in[0];
    const int* ei    = (const int*)d_in[1];
    const float* ew  = (const float*)d_in[2];
    const float* Wm[3] = {(const float*)d_in[3], (const float*)d_in[6], (const float*)d_in[9]};
    const float* Wu[3] = {(const float*)d_in[4], (const float*)d_in[7], (const float*)d_in[10]};
    const float* bu[3] = {(const float*)d_in[5], (const float*)d_in[8], (const float*)d_in[11]};
    const float* Wout = (const float*)d_in[12];
    const float* bout = (const float*)d_in[13];
    float* out = (float*)d_out;

    const int N = in_sizes[0] / 128;
    const int E = in_sizes[2];
    const size_t NPAD = 50048;
    const int NB = (N + BSZ - 1) / BSZ;  // 196 buckets
    const int TI = NB * TSTRIDE + 16;    // tails + cursor (zeroed together)

    ushort_t* xb    = (ushort_t*)d_ws;              // [NPAD,128] bf16
    ushort_t* hA    = xb + NPAD * 128;
    ushort_t* hB    = hA + NPAD * 128;
    ushort_t* wswz  = hB + NPAD * 128;              // 3*32768 bf16
    ushort_t* woswz = wswz + 3 * 32768;             // 4096 bf16
    int* flag       = (int*)(woswz + 4096);
    int* tails      = flag + 1;
    int* cursor     = tails + NB * TSTRIDE;         // inside zeroed TI range
    int* endp       = tails + TI;
    int2* rowdeg    = (int2*)(((uintptr_t)endp + 7) & ~(uintptr_t)7);
    uint2* staged   = (uint2*)(rowdeg + N + 8);
    uint_t* csr     = (uint_t*)(staged + (size_t)NB * CAPB);
    (void)ws_size;

    const int ZT = (TI + 255) / 256;
    const int WB = (3 * 32768 + 4096 + 255) / 256;  // 400
    const int XB = (N * 32 + 255) / 256;            // 6250
    const int gB = (E + EPB - 1) / EPB;             // 391
    const int gG = (N + 63) / 64;                   // 782
    const int gO = (N + 63) / 64;                   // 782

    SetupArgs sa;
    sa.Wm0 = Wm[0]; sa.Wu0 = Wu[0];
    sa.Wm1 = Wm[1]; sa.Wu1 = Wu[1];
    sa.Wm2 = Wm[2]; sa.Wu2 = Wu[2];
    sa.Wout = Wout; sa.x = x; sa.ei = ei;
    sa.wswz = wswz; sa.woswz = woswz; sa.xb = xb;
    sa.tails = tails; sa.flag = flag;
    sa.N = N; sa.E = E; sa.TI = TI;
    sa.ZT = ZT; sa.WB = WB; sa.XB = XB;
    setup_kernel<<<ZT + 1 + WB + XB, 256, 0, stream>>>(sa);

    bin_kernel<<<gB, 256, 0, stream>>>(ei, ew, flag, tails, staged, E, NB);
    place_kernel<<<NB, 256, 0, stream>>>(staged, tails, cursor, csr, rowdeg, N);

    const ushort_t* hin[3] = {xb, hA, hB};
    ushort_t* hout[3] = {hA, hB, hA};
    for (int l = 0; l < 3; ++l) {
        layer_fused<<<gG, 256, 0, stream>>>(csr, rowdeg, hin[l],
                                            wswz + (size_t)l * 32768,
                                            bu[l], hout[l], N);
    }
    mfma_gemm_out<<<gO, 256, 0, stream>>>(hA, woswz, bout, out, N);
}